// Round 1
// 1711.887 us; speedup vs baseline: 2.1796x; 2.1796x over previous
//
#include <hip/hip_runtime.h>

typedef unsigned short u16;
typedef short bf16x8 __attribute__((ext_vector_type(8)));
typedef float f32x4 __attribute__((ext_vector_type(4)));

#define BM 64
#define BN 64
#define BK 32
#define ADJ_LD 66

__device__ __forceinline__ float bf2f(u16 u) {
    union { unsigned int i; float f; } x;
    x.i = ((unsigned int)u) << 16;
    return x.f;
}
__device__ __forceinline__ u16 f2bf(float f) {
    union { float f; unsigned int i; } x;
    x.f = f;
    unsigned int i = x.i;
    i += 0x7fffu + ((i >> 16) & 1u);  // RNE
    return (u16)(i >> 16);
}

#define GLOAD16(g, l) __builtin_amdgcn_global_load_lds( \
    (__attribute__((address_space(1))) void*)(g), \
    (__attribute__((address_space(3))) void*)(l), 16, 0, 0)

// ======================= FAST PATH =======================

// dst[row, 0:Kpad] = bf16(src[row, srcoff : srcoff+K]), zero-padded to Kpad.
__global__ __launch_bounds__(256) void convert_a_kernel(
    const float* __restrict__ src, int ld, int srcoff,
    u16* __restrict__ dst, int K, int Kpad, int rows)
{
    const int perrow = Kpad >> 3;
    const int total = rows * perrow;
    for (int idx = blockIdx.x * 256 + threadIdx.x; idx < total; idx += gridDim.x * 256) {
        const int row = idx / perrow;
        const int c8  = (idx - row * perrow) << 3;
        u16 o[8];
        if (c8 + 8 <= K) {
            const float* s = src + (size_t)row * ld + srcoff + c8;
            float4 v0 = *(const float4*)s;
            float4 v1 = *(const float4*)(s + 4);
            o[0] = f2bf(v0.x); o[1] = f2bf(v0.y); o[2] = f2bf(v0.z); o[3] = f2bf(v0.w);
            o[4] = f2bf(v1.x); o[5] = f2bf(v1.y); o[6] = f2bf(v1.z); o[7] = f2bf(v1.w);
        } else {
            #pragma unroll
            for (int q = 0; q < 8; ++q)
                o[q] = (c8 + q < K) ? f2bf(src[(size_t)row * ld + srcoff + c8 + q]) : (u16)0;
        }
        *(uint4*)&dst[(size_t)row * Kpad + c8] = *(const uint4*)o;
    }
}

// Wm[n, k] = bf16(W[n,k] * adj[k,n]), written over the full padded (Npad x Kpad)
// footprint (pad rows/cols = 0). adj may be null (dense convert).
__global__ __launch_bounds__(256) void mask_weight_kernel(
    const float* __restrict__ W, const float* __restrict__ adj,
    u16* __restrict__ Wm, int N, int K, int Kpad)
{
    __shared__ float adjS[64][65];
    const int t  = threadIdx.x;
    const int k0 = blockIdx.x * 64;
    const int n0 = blockIdx.y * 64;
    const int i0 = t >> 4;          // 0..15
    const int j4 = (t & 15) * 4;    // 0,4,..60

    if (adj) {
        #pragma unroll
        for (int r = 0; r < 4; ++r) {
            const int a  = i0 + 16 * r;      // k-local
            const int kg = k0 + a;
            float4 v = make_float4(0.f, 0.f, 0.f, 0.f);
            if (kg < K && n0 + j4 < N)       // N,K multiples of 4 -> full float4 valid
                v = *(const float4*)&adj[(size_t)kg * N + n0 + j4];
            adjS[a][j4 + 0] = v.x; adjS[a][j4 + 1] = v.y;
            adjS[a][j4 + 2] = v.z; adjS[a][j4 + 3] = v.w;
        }
        __syncthreads();
    }
    #pragma unroll
    for (int r = 0; r < 4; ++r) {
        const int i  = i0 + 16 * r;          // n-local
        const int n  = n0 + i;
        const int kg = k0 + j4;
        float w[4] = {0.f, 0.f, 0.f, 0.f};
        if (n < N && kg < K) {
            const float4 v = *(const float4*)&W[(size_t)n * K + kg];
            w[0] = v.x; w[1] = v.y; w[2] = v.z; w[3] = v.w;
        }
        float m[4] = {1.f, 1.f, 1.f, 1.f};
        if (adj) {
            m[0] = adjS[j4 + 0][i]; m[1] = adjS[j4 + 1][i];
            m[2] = adjS[j4 + 2][i]; m[3] = adjS[j4 + 3][i];
        }
        ushort4 o;
        o.x = f2bf(w[0] * m[0]); o.y = f2bf(w[1] * m[1]);
        o.z = f2bf(w[2] * m[2]); o.w = f2bf(w[3] * m[3]);
        *(ushort4*)&Wm[(size_t)n * Kpad + kg] = o;
    }
}

__global__ void zero_pad_kernel(u16* __restrict__ buf, int ld, int start, int count, int rows)
{
    const int idx = blockIdx.x * blockDim.x + threadIdx.x;
    const int total = rows * count;
    if (idx < total) {
        const int row = idx / count;
        const int c   = idx - row * count;
        buf[(size_t)row * ld + start + c] = 0;
    }
}

// C[m, c_off+n] = relu(A @ B^T + bias). A: (>=m0+64) x Kpad bf16, zero K-pad.
// B: Npad x Kpad bf16, zero pad. 64x64 tile, BK=64, global_load_lds(16B),
// XOR-swizzled LDS (linear dest + inverse-swizzled source + swizzled read).
__global__ __launch_bounds__(256) void gemm_bf16_kernel(
    const u16* __restrict__ A, int lda,
    const u16* __restrict__ B, int ldb,
    const float* __restrict__ bias,
    u16* __restrict__ C, int ldc, int c_off,
    int N, int Kpad)
{
    __shared__ __align__(16) u16 As[64 * 64];
    __shared__ __align__(16) u16 Bs[64 * 64];

    const int t    = threadIdx.x;
    const int lane = t & 63;
    const int wave = t >> 6;
    const int m0 = blockIdx.y * 64;
    const int n0 = blockIdx.x * 64;

    // staging: wave w covers rows 16w..16w+15 in 2 issues of 8 rows.
    // LDS dest linear: base + lane*16. Global source slot pre-swizzled so that
    // LDS(row, slot) holds global(row, slot ^ (row&7)).
    const int srow = lane >> 3;                       // 0..7
    const int scol = (((lane & 7) ^ srow) << 4);      // swizzled byte col

    const char* Ag0 = (const char*)(A + (size_t)(m0 + 16 * wave) * lda);
    const char* Bg0 = (const char*)(B + (size_t)(n0 + 16 * wave) * ldb);
    const size_t lda2 = (size_t)lda * 2, ldb2 = (size_t)ldb * 2;

    char* AsB = (char*)As + 16 * wave * 128 + lane * 16;
    char* BsB = (char*)Bs + 16 * wave * 128 + lane * 16;

    const int wr = wave >> 1, wc = wave & 1;
    const int fr = lane & 15, fq = lane >> 4;
    const int sx = (fr & 7) << 4;                     // read-side swizzle

    const char* AsR = (const char*)As + (wr * 32 + fr) * 128;
    const char* BsR = (const char*)Bs + (wc * 32 + fr) * 128;

    f32x4 acc[2][2] = {};
    const int nk = Kpad >> 6;
    for (int kt = 0; kt < nk; ++kt) {
        const size_t kb = (size_t)kt << 7;            // *128 bytes
        __syncthreads();
        GLOAD16(Ag0 + (size_t)srow * lda2 + kb + scol, AsB);
        GLOAD16(Ag0 + (size_t)(8 + srow) * lda2 + kb + scol, AsB + 1024);
        GLOAD16(Bg0 + (size_t)srow * ldb2 + kb + scol, BsB);
        GLOAD16(Bg0 + (size_t)(8 + srow) * ldb2 + kb + scol, BsB + 1024);
        __syncthreads();                              // drains vmcnt
        #pragma unroll
        for (int kk = 0; kk < 2; ++kk) {
            const int ko = (kk * 64 + fq * 16) ^ sx;
            bf16x8 a0 = *(const bf16x8*)(AsR + ko);
            bf16x8 a1 = *(const bf16x8*)(AsR + 16 * 128 + ko);
            bf16x8 b0 = *(const bf16x8*)(BsR + ko);
            bf16x8 b1 = *(const bf16x8*)(BsR + 16 * 128 + ko);
            acc[0][0] = __builtin_amdgcn_mfma_f32_16x16x32_bf16(a0, b0, acc[0][0], 0, 0, 0);
            acc[0][1] = __builtin_amdgcn_mfma_f32_16x16x32_bf16(a0, b1, acc[0][1], 0, 0, 0);
            acc[1][0] = __builtin_amdgcn_mfma_f32_16x16x32_bf16(a1, b0, acc[1][0], 0, 0, 0);
            acc[1][1] = __builtin_amdgcn_mfma_f32_16x16x32_bf16(a1, b1, acc[1][1], 0, 0, 0);
        }
    }

    #pragma unroll
    for (int tn = 0; tn < 2; ++tn) {
        const int gcol = n0 + wc * 32 + tn * 16 + fr;
        if (gcol >= N) continue;
        const float bv = bias[gcol];
        #pragma unroll
        for (int tm = 0; tm < 2; ++tm) {
            #pragma unroll
            for (int r = 0; r < 4; ++r) {
                const int grow = m0 + wr * 32 + tm * 16 + fq * 4 + r;
                float v = acc[tm][tn][r] + bv;
                v = v > 0.f ? v : 0.f;
                C[(size_t)grow * ldc + c_off + gcol] = f2bf(v);
            }
        }
    }
}

// ======================= FALLBACK (previous verified kernel) =======================

__global__ __launch_bounds__(256) void masked_gemm_kernel(
    const void* __restrict__ Av, int lda, int a_off, int a_f32,
    const float* __restrict__ W,
    const float* __restrict__ adj,
    const float* __restrict__ bias,
    u16* __restrict__ C, int ldc, int c_off,
    int N, int K)
{
    __shared__ __align__(16) u16 As[BM * BK];
    __shared__ __align__(16) u16 Bs[BN * BK];
    __shared__ __align__(16) u16 adjS[BK * ADJ_LD];

    const int t  = threadIdx.x;
    const int m0 = blockIdx.y * BM;
    const int n0 = blockIdx.x * BN;

    const int am = t >> 2;
    const int ak = (t & 3) * 8;
    const bool wvalid = (n0 + am) < N;
    const int jk = t >> 3;
    const int jn = (t & 7) * 8;

    const int lane  = t & 63;
    const int wave  = t >> 6;
    const int wm    = (wave >> 1) * 32;
    const int wnoff = (wave & 1) * 32;
    const int fr    = lane & 15;
    const int fq    = lane >> 4;
    const int kq    = fq * 8;

    const float* Af = (const float*)Av + (size_t)(m0 + am) * lda + a_off;
    const u16*   Ah = (const u16*)Av + (size_t)(m0 + am) * lda + a_off;
    const float* Wrow = W + (size_t)(n0 + am) * K;

    f32x4 acc[2][2] = {};

    const int nk = (K + BK - 1) / BK;
    for (int kt = 0; kt < nk; ++kt) {
        const int k0 = kt * BK;
        __syncthreads();
        {
            const int kg = k0 + ak;
            u16* dst = &As[am * BK + ak];
            if (a_f32) {
                if (kg + 8 <= K) {
                    float4 u0 = *(const float4*)&Af[kg];
                    float4 u1 = *(const float4*)&Af[kg + 4];
                    u16 tmp[8] = { f2bf(u0.x), f2bf(u0.y), f2bf(u0.z), f2bf(u0.w),
                                   f2bf(u1.x), f2bf(u1.y), f2bf(u1.z), f2bf(u1.w) };
                    *(uint4*)dst = *(const uint4*)tmp;
                } else {
                    #pragma unroll
                    for (int j = 0; j < 8; ++j)
                        dst[j] = (kg + j < K) ? f2bf(Af[kg + j]) : (u16)0;
                }
            } else {
                if (kg + 8 <= K) {
                    *(uint4*)dst = *(const uint4*)&Ah[kg];
                } else {
                    #pragma unroll
                    for (int j = 0; j < 8; ++j)
                        dst[j] = (kg + j < K) ? Ah[kg + j] : (u16)0;
                }
            }
        }
        {
            const int kg = k0 + ak;
            u16* dst = &Bs[am * BK + ak];
            if (wvalid && kg + 8 <= K) {
                float4 u0 = *(const float4*)&Wrow[kg];
                float4 u1 = *(const float4*)&Wrow[kg + 4];
                u16 tmp[8] = { f2bf(u0.x), f2bf(u0.y), f2bf(u0.z), f2bf(u0.w),
                               f2bf(u1.x), f2bf(u1.y), f2bf(u1.z), f2bf(u1.w) };
                *(uint4*)dst = *(const uint4*)tmp;
            } else {
                #pragma unroll
                for (int j = 0; j < 8; ++j)
                    dst[j] = (wvalid && kg + j < K) ? f2bf(Wrow[kg + j]) : (u16)0;
            }
        }
        if (adj) {
            const int kg = k0 + jk;
            u16* dst = &adjS[jk * ADJ_LD + jn];
            if (kg < K && n0 + jn + 8 <= N) {
                const float* ap = &adj[(size_t)kg * N + n0 + jn];
                float4 u0 = *(const float4*)&ap[0];
                float4 u1 = *(const float4*)&ap[4];
                u16 tmp[8] = { (u16)(u0.x != 0.f), (u16)(u0.y != 0.f),
                               (u16)(u0.z != 0.f), (u16)(u0.w != 0.f),
                               (u16)(u1.x != 0.f), (u16)(u1.y != 0.f),
                               (u16)(u1.z != 0.f), (u16)(u1.w != 0.f) };
                *(uint4*)dst = *(const uint4*)tmp;
            } else {
                #pragma unroll
                for (int j = 0; j < 8; ++j)
                    dst[j] = (kg < K && n0 + jn + j < N)
                                 ? (u16)(adj[(size_t)kg * N + n0 + jn + j] != 0.f) : (u16)0;
            }
            __syncthreads();
            #pragma unroll
            for (int j = 0; j < 8; ++j) {
                if (adjS[(ak + j) * ADJ_LD + am] == 0)
                    Bs[am * BK + ak + j] = 0;
            }
        }
        __syncthreads();

        bf16x8 a0 = *(const bf16x8*)&As[(wm + fr) * BK + kq];
        bf16x8 a1 = *(const bf16x8*)&As[(wm + 16 + fr) * BK + kq];
        bf16x8 b0 = *(const bf16x8*)&Bs[(wnoff + fr) * BK + kq];
        bf16x8 b1 = *(const bf16x8*)&Bs[(wnoff + 16 + fr) * BK + kq];
        acc[0][0] = __builtin_amdgcn_mfma_f32_16x16x32_bf16(a0, b0, acc[0][0], 0, 0, 0);
        acc[0][1] = __builtin_amdgcn_mfma_f32_16x16x32_bf16(a0, b1, acc[0][1], 0, 0, 0);
        acc[1][0] = __builtin_amdgcn_mfma_f32_16x16x32_bf16(a1, b0, acc[1][0], 0, 0, 0);
        acc[1][1] = __builtin_amdgcn_mfma_f32_16x16x32_bf16(a1, b1, acc[1][1], 0, 0, 0);
    }

    #pragma unroll
    for (int tn = 0; tn < 2; ++tn) {
        const int gcol = n0 + wnoff + tn * 16 + fr;
        if (gcol >= N) continue;
        const float bv = bias[gcol];
        #pragma unroll
        for (int tm = 0; tm < 2; ++tm) {
            #pragma unroll
            for (int r = 0; r < 4; ++r) {
                const int grow = m0 + wm + tm * 16 + fq * 4 + r;
                float v = acc[tm][tn][r] + bv;
                v = v > 0.f ? v : 0.f;
                C[(size_t)grow * ldc + c_off + gcol] = f2bf(v);
            }
        }
    }
}

__global__ __launch_bounds__(64) void final_kernel(
    const u16* __restrict__ h2, const float* __restrict__ Wout,
    const float* __restrict__ bout, float* __restrict__ out)
{
    const int r = blockIdx.x;
    const int lane = threadIdx.x;
    float s = 0.f;
    #pragma unroll
    for (int j = 0; j < 4; ++j) {
        const int k = lane * 4 + j;
        s += bf2f(h2[r * 256 + k]) * Wout[k];
    }
    #pragma unroll
    for (int off = 32; off > 0; off >>= 1)
        s += __shfl_down(s, off, 64);
    if (lane == 0) {
        const float x = s + bout[0];
        out[r] = 1.f / (1.f + __expf(-x));
    }
}

// ======================= LAUNCH =======================

extern "C" void kernel_launch(void* const* d_in, const int* in_sizes, int n_in,
                              void* d_out, int out_size, void* d_ws, size_t ws_size,
                              hipStream_t stream) {
    const float* in_mat = (const float*)d_in[0];         // f32 512x28000
    const float* adj_sg = (const float*)d_in[1];
    const float* adj_gp = (const float*)d_in[2];
    const float* adj_br = (const float*)d_in[3];
    const float* adj_pp = (const float*)d_in[4];
    const float* W_sg = (const float*)d_in[5];   const float* b_sg = (const float*)d_in[6];
    const float* W_gp = (const float*)d_in[7];   const float* b_gp = (const float*)d_in[8];
    const float* W_br = (const float*)d_in[9];   const float* b_br = (const float*)d_in[10];
    const float* W_pp = (const float*)d_in[11];  const float* b_pp = (const float*)d_in[12];
    const float* W_h1 = (const float*)d_in[13];  const float* b_h1 = (const float*)d_in[14];
    const float* W_h2 = (const float*)d_in[15];  const float* b_h2 = (const float*)d_in[16];
    const float* W_out = (const float*)d_in[17]; const float* b_out = (const float*)d_in[18];

    // padded dims (multiples of 64 in K and N)
    const int KP_SG = 20032, KP_GP = 5056, KP_BR = 8000, KP_PP = 3008, KP_H1 = 6016, KP_H2 = 1024;
    const int NP_SG = 5056,  NP_GP = 3008, NP_BR = 3008, NP_PP = 3008, NP_H1 = 1024, NP_H2 = 256;

    u16* p = (u16*)d_ws;
    u16* Asnp = p;  p += (size_t)512 * KP_SG;
    u16* Agen = p;  p += (size_t)512 * KP_GP;
    u16* Apro = p;  p += (size_t)512 * KP_PP;
    u16* Wsg  = p;  p += (size_t)NP_SG * KP_SG;
    u16* Wgp  = p;  p += (size_t)NP_GP * KP_GP;
    u16* Wbr  = p;  p += (size_t)NP_BR * KP_BR;
    u16* Wpp  = p;  p += (size_t)NP_PP * KP_PP;
    u16* Wh1  = p;  p += (size_t)NP_H1 * KP_H1;
    u16* Wh2  = p;  p += (size_t)NP_H2 * KP_H2;
    u16* bridge = p; p += (size_t)512 * 8000;
    u16* fuse   = p; p += (size_t)512 * KP_H1;   // 512 x 6016
    u16* h1c    = p; p += (size_t)512 * 1024;
    u16* h2c    = p; p += (size_t)512 * 256;
    const size_t need_bytes = (size_t)(p - (u16*)d_ws) * 2;

    const dim3 blk(256);
    if (ws_size >= need_bytes) {
        // ---- pre-pass: activations f32 -> padded bf16 ----
        convert_a_kernel<<<dim3(2048), blk, 0, stream>>>(in_mat, 28000, 8000, Asnp, 20000, KP_SG, 512);
        convert_a_kernel<<<dim3(1264), blk, 0, stream>>>(in_mat, 28000, 3000, Agen, 5000, KP_GP, 512);
        convert_a_kernel<<<dim3(752),  blk, 0, stream>>>(in_mat, 28000, 0,    Apro, 3000, KP_PP, 512);
        // ---- pre-pass: masked weights -> padded bf16 (n-major) ----
        mask_weight_kernel<<<dim3(KP_SG / 64, NP_SG / 64), blk, 0, stream>>>(W_sg, adj_sg, Wsg, 5000, 20000, KP_SG);
        mask_weight_kernel<<<dim3(KP_GP / 64, NP_GP / 64), blk, 0, stream>>>(W_gp, adj_gp, Wgp, 3000, 5000, KP_GP);
        mask_weight_kernel<<<dim3(KP_BR / 64, NP_BR / 64), blk, 0, stream>>>(W_br, adj_br, Wbr, 3000, 8000, KP_BR);
        mask_weight_kernel<<<dim3(KP_PP / 64, NP_PP / 64), blk, 0, stream>>>(W_pp, adj_pp, Wpp, 3000, 3000, KP_PP);
        mask_weight_kernel<<<dim3(KP_H1 / 64, NP_H1 / 64), blk, 0, stream>>>(W_h1, nullptr, Wh1, 1024, 6000, KP_H1);
        mask_weight_kernel<<<dim3(KP_H2 / 64, NP_H2 / 64), blk, 0, stream>>>(W_h2, nullptr, Wh2, 256, 1024, KP_H2);
        zero_pad_kernel<<<dim3(32), blk, 0, stream>>>(fuse, KP_H1, 6000, 16, 512);

        // ---- GEMM chain ----
        gemm_bf16_kernel<<<dim3(79, 8), blk, 0, stream>>>(Asnp, KP_SG, Wsg, KP_SG, b_sg, bridge, 8000, 0, 5000, KP_SG);
        gemm_bf16_kernel<<<dim3(47, 8), blk, 0, stream>>>(Agen, KP_GP, Wgp, KP_GP, b_gp, bridge, 8000, 5000, 3000, KP_GP);
        gemm_bf16_kernel<<<dim3(47, 8), blk, 0, stream>>>(bridge, 8000, Wbr, KP_BR, b_br, fuse, KP_H1, 0, 3000, KP_BR);
        gemm_bf16_kernel<<<dim3(47, 8), blk, 0, stream>>>(Apro, KP_PP, Wpp, KP_PP, b_pp, fuse, KP_H1, 3000, 3000, KP_PP);
        gemm_bf16_kernel<<<dim3(16, 8), blk, 0, stream>>>(fuse, KP_H1, Wh1, KP_H1, b_h1, h1c, 1024, 0, 1024, KP_H1);
        gemm_bf16_kernel<<<dim3(4, 8),  blk, 0, stream>>>(h1c, 1024, Wh2, KP_H2, b_h2, h2c, 256, 0, 256, KP_H2);
        final_kernel<<<dim3(512), dim3(64), 0, stream>>>(h2c, W_out, b_out, (float*)d_out);
    } else {
        // ---- fallback: previous verified path ----
        u16* ws      = (u16*)d_ws;
        u16* bridgeF = ws;
        u16* fuseF   = bridgeF + (size_t)512 * 8000;
        u16* h1F     = fuseF + (size_t)512 * 6000;
        u16* h2F     = h1F + (size_t)512 * 1024;

        masked_gemm_kernel<<<dim3((5000 + 63) / 64, 8), blk, 0, stream>>>(
            in_mat, 28000, 8000, 1, W_sg, adj_sg, b_sg, bridgeF, 8000, 0, 5000, 20000);
        masked_gemm_kernel<<<dim3((3000 + 63) / 64, 8), blk, 0, stream>>>(
            in_mat, 28000, 3000, 1, W_gp, adj_gp, b_gp, bridgeF, 8000, 5000, 3000, 5000);
        masked_gemm_kernel<<<dim3((3000 + 63) / 64, 8), blk, 0, stream>>>(
            bridgeF, 8000, 0, 0, W_br, adj_br, b_br, fuseF, 6000, 0, 3000, 8000);
        masked_gemm_kernel<<<dim3((3000 + 63) / 64, 8), blk, 0, stream>>>(
            in_mat, 28000, 0, 1, W_pp, adj_pp, b_pp, fuseF, 6000, 3000, 3000, 3000);
        masked_gemm_kernel<<<dim3(1024 / 64, 8), blk, 0, stream>>>(
            fuseF, 6000, 0, 0, W_h1, nullptr, b_h1, h1F, 1024, 0, 1024, 6000);
        masked_gemm_kernel<<<dim3(256 / 64, 8), blk, 0, stream>>>(
            h1F, 1024, 0, 0, W_h2, nullptr, b_h2, h2F, 256, 0, 256, 1024);
        final_kernel<<<dim3(512), dim3(64), 0, stream>>>(h2F, W_out, b_out, (float*)d_out);
    }
}

// Round 2
// 1611.693 us; speedup vs baseline: 2.3151x; 1.0622x over previous
//
#include <hip/hip_runtime.h>

typedef unsigned short u16;
typedef short bf16x8 __attribute__((ext_vector_type(8)));
typedef float f32x4 __attribute__((ext_vector_type(4)));

__device__ __forceinline__ float bf2f(u16 u) {
    union { unsigned int i; float f; } x;
    x.i = ((unsigned int)u) << 16;
    return x.f;
}
__device__ __forceinline__ u16 f2bf(float f) {
    union { float f; unsigned int i; } x;
    x.f = f;
    unsigned int i = x.i;
    i += 0x7fffu + ((i >> 16) & 1u);  // RNE
    return (u16)(i >> 16);
}

#define GLOAD16(g, l) __builtin_amdgcn_global_load_lds( \
    (__attribute__((address_space(1))) void*)(g), \
    (__attribute__((address_space(3))) void*)(l), 16, 0, 0)

// ======================= PREP (masks + converts + pad, one launch) =======================

struct PrepTask {
    int type;              // 0=mask, 1=convert, 2=zeropad
    const float* a;        // W | src | -
    const float* b;        // adj | - | -
    u16* dst;
    int N, K, Kpad, ld, off, base, cnt;
};
struct PrepBatch { PrepTask t[10]; int ntask; };

__global__ __launch_bounds__(256) void prep_kernel(PrepBatch pb)
{
    __shared__ float adjS[64][65];
    const int bid = blockIdx.x;
    int ti = 0;
    #pragma unroll
    for (int i = 1; i < 10; ++i)
        if (i < pb.ntask && bid >= pb.t[i].base) ti = i;
    const PrepTask tk = pb.t[ti];
    const int local = bid - tk.base;
    const int t = threadIdx.x;

    if (tk.type == 0) {
        // ---- mask: Wm[n,k] = bf16(W[n,k] * adj[k,n]) over padded footprint ----
        const int nx = tk.Kpad >> 6;
        const int k0 = (local % nx) * 64;
        const int n0 = (local / nx) * 64;
        const int i0 = t >> 4;
        const int j4 = (t & 15) * 4;
        if (tk.b) {
            #pragma unroll
            for (int r = 0; r < 4; ++r) {
                const int a  = i0 + 16 * r;
                const int kg = k0 + a;
                float4 v = make_float4(0.f, 0.f, 0.f, 0.f);
                if (kg < tk.K && n0 + j4 < tk.N)
                    v = *(const float4*)&tk.b[(size_t)kg * tk.N + n0 + j4];
                adjS[a][j4 + 0] = v.x; adjS[a][j4 + 1] = v.y;
                adjS[a][j4 + 2] = v.z; adjS[a][j4 + 3] = v.w;
            }
            __syncthreads();
        }
        #pragma unroll
        for (int r = 0; r < 4; ++r) {
            const int i  = i0 + 16 * r;
            const int n  = n0 + i;
            const int kg = k0 + j4;
            float w[4] = {0.f, 0.f, 0.f, 0.f};
            if (n < tk.N && kg < tk.K) {
                const float4 v = *(const float4*)&tk.a[(size_t)n * tk.K + kg];
                w[0] = v.x; w[1] = v.y; w[2] = v.z; w[3] = v.w;
            }
            float m[4] = {1.f, 1.f, 1.f, 1.f};
            if (tk.b) {
                m[0] = adjS[j4 + 0][i]; m[1] = adjS[j4 + 1][i];
                m[2] = adjS[j4 + 2][i]; m[3] = adjS[j4 + 3][i];
            }
            ushort4 o;
            o.x = f2bf(w[0] * m[0]); o.y = f2bf(w[1] * m[1]);
            o.z = f2bf(w[2] * m[2]); o.w = f2bf(w[3] * m[3]);
            *(ushort4*)&tk.dst[(size_t)n * tk.Kpad + kg] = o;
        }
    } else if (tk.type == 1) {
        // ---- convert: dst[row, 0:Kpad] = bf16(src[row, off:off+K]), zero K-pad ----
        const int perrow = tk.Kpad >> 3;
        const int total = 512 * perrow;
        for (int idx = local * 256 + t; idx < total; idx += tk.cnt * 256) {
            const int row = idx / perrow;
            const int c8  = (idx - row * perrow) << 3;
            u16 o[8];
            if (c8 + 8 <= tk.K) {
                const float* s = tk.a + (size_t)row * tk.ld + tk.off + c8;
                float4 v0 = *(const float4*)s;
                float4 v1 = *(const float4*)(s + 4);
                o[0] = f2bf(v0.x); o[1] = f2bf(v0.y); o[2] = f2bf(v0.z); o[3] = f2bf(v0.w);
                o[4] = f2bf(v1.x); o[5] = f2bf(v1.y); o[6] = f2bf(v1.z); o[7] = f2bf(v1.w);
            } else {
                #pragma unroll
                for (int q = 0; q < 8; ++q)
                    o[q] = (c8 + q < tk.K) ? f2bf(tk.a[(size_t)row * tk.ld + tk.off + c8 + q]) : (u16)0;
            }
            *(uint4*)&tk.dst[(size_t)row * tk.Kpad + c8] = *(const uint4*)o;
        }
    } else {
        // ---- zeropad: dst[row, off:off+K] = 0 for 512 rows ----
        const int idx = local * 256 + t;
        const int total = 512 * tk.K;
        if (idx < total) {
            const int row = idx / tk.K;
            const int c   = idx - row * tk.K;
            tk.dst[(size_t)row * tk.ld + tk.off + c] = 0;
        }
    }
}

// ======================= PIPELINED GEMM =======================
// C[m, c_off+n] = relu(A @ B^T + bias). A: 512 x Kpad bf16 (zero K-pad),
// B: Npad x Kpad bf16 (zero pad). 64x64 tile, BK=64, global_load_lds(16B),
// XOR-swizzled LDS, 3-buffer depth-2 prefetch with counted vmcnt + raw s_barrier.
// Grid: m-tile fastest (local&7) so 8 sharers of a B panel are consecutive.

struct GemmTask {
    const u16* A; const u16* B; const float* bias; u16* C;
    int lda, ldb, ldc, c_off, N, nk, base;
};
struct GemmBatch { GemmTask t[3]; int ntask; };

__global__ __launch_bounds__(256) void gemm_bf16_kernel(GemmBatch gb)
{
    __shared__ __align__(16) u16 As[3][64 * 64];
    __shared__ __align__(16) u16 Bs[3][64 * 64];

    const int t    = threadIdx.x;
    const int lane = t & 63;
    const int wave = t >> 6;

    int ti = 0;
    if (gb.ntask > 1 && (int)blockIdx.x >= gb.t[1].base) ti = 1;
    if (gb.ntask > 2 && (int)blockIdx.x >= gb.t[2].base) ti = 2;
    const GemmTask tk = gb.t[ti];
    const int local = (int)blockIdx.x - tk.base;
    const int m0 = (local & 7) * 64;      // m-tile fastest -> B-panel LLC reuse
    const int n0 = (local >> 3) * 64;

    // staging: wave w covers rows 16w..16w+15 in 2 issues of 8 rows; LDS dest linear,
    // global source slot pre-swizzled so LDS(row, slot) = global(row, slot ^ (row&7)).
    const int srow = lane >> 3;
    const int scol = (((lane & 7) ^ srow) << 4);

    const char* Ag0 = (const char*)(tk.A + (size_t)(m0 + 16 * wave) * tk.lda);
    const char* Bg0 = (const char*)(tk.B + (size_t)(n0 + 16 * wave) * tk.ldb);
    const size_t lda2 = (size_t)tk.lda * 2, ldb2 = (size_t)tk.ldb * 2;
    const size_t aoff0 = (size_t)srow * lda2 + scol;
    const size_t aoff1 = (size_t)(8 + srow) * lda2 + scol;
    const size_t boff0 = (size_t)srow * ldb2 + scol;
    const size_t boff1 = (size_t)(8 + srow) * ldb2 + scol;
    const int sb = 16 * wave * 128 + lane * 16;

    const int wr = wave >> 1, wc = wave & 1;
    const int fr = lane & 15, fq = lane >> 4;
    const int sx = (fr & 7) << 4;
    const int rA = (wr * 32 + fr) * 128;
    const int rB = (wc * 32 + fr) * 128;

    f32x4 acc[2][2] = {};
    const int nk = tk.nk;

#define STAGE(tt, bb) do { \
        const size_t kb = (size_t)(tt) << 7; \
        GLOAD16(Ag0 + kb + aoff0, (char*)As[bb] + sb); \
        GLOAD16(Ag0 + kb + aoff1, (char*)As[bb] + sb + 1024); \
        GLOAD16(Bg0 + kb + boff0, (char*)Bs[bb] + sb); \
        GLOAD16(Bg0 + kb + boff1, (char*)Bs[bb] + sb + 1024); \
    } while (0)

    STAGE(0, 0);
    if (nk > 1) STAGE(1, 1);

    for (int kt = 0; kt < nk; ++kt) {
        const int cb = kt % 3;
        if (kt + 2 < nk) STAGE(kt + 2, (kt + 2) % 3);
        const int ahead = nk - 1 - kt;
        if (ahead >= 2)      asm volatile("s_waitcnt vmcnt(8)" ::: "memory");
        else if (ahead == 1) asm volatile("s_waitcnt vmcnt(4)" ::: "memory");
        else                 asm volatile("s_waitcnt vmcnt(0)" ::: "memory");
        __builtin_amdgcn_sched_barrier(0);
        __builtin_amdgcn_s_barrier();     // all waves' current-tile loads landed

        const char* AsR = (const char*)As[cb] + rA;
        const char* BsR = (const char*)Bs[cb] + rB;
        #pragma unroll
        for (int kk = 0; kk < 2; ++kk) {
            const int ko = (kk * 64 + fq * 16) ^ sx;
            bf16x8 a0 = *(const bf16x8*)(AsR + ko);
            bf16x8 a1 = *(const bf16x8*)(AsR + 16 * 128 + ko);
            bf16x8 b0 = *(const bf16x8*)(BsR + ko);
            bf16x8 b1 = *(const bf16x8*)(BsR + 16 * 128 + ko);
            acc[0][0] = __builtin_amdgcn_mfma_f32_16x16x32_bf16(a0, b0, acc[0][0], 0, 0, 0);
            acc[0][1] = __builtin_amdgcn_mfma_f32_16x16x32_bf16(a0, b1, acc[0][1], 0, 0, 0);
            acc[1][0] = __builtin_amdgcn_mfma_f32_16x16x32_bf16(a1, b0, acc[1][0], 0, 0, 0);
            acc[1][1] = __builtin_amdgcn_mfma_f32_16x16x32_bf16(a1, b1, acc[1][1], 0, 0, 0);
        }
        __builtin_amdgcn_s_barrier();     // all reads of buf[cb] done before reuse
    }
#undef STAGE

    #pragma unroll
    for (int tn = 0; tn < 2; ++tn) {
        const int gcol = n0 + wc * 32 + tn * 16 + fr;
        if (gcol >= tk.N) continue;
        const float bv = tk.bias[gcol];
        #pragma unroll
        for (int tm = 0; tm < 2; ++tm) {
            #pragma unroll
            for (int r = 0; r < 4; ++r) {
                const int grow = m0 + wr * 32 + tm * 16 + fq * 4 + r;
                float v = acc[tm][tn][r] + bv;
                v = v > 0.f ? v : 0.f;
                tk.C[(size_t)grow * tk.ldc + tk.c_off + gcol] = f2bf(v);
            }
        }
    }
}

// ======================= FINAL =======================

__global__ __launch_bounds__(64) void final_kernel(
    const u16* __restrict__ h2, const float* __restrict__ Wout,
    const float* __restrict__ bout, float* __restrict__ out)
{
    const int r = blockIdx.x;
    const int lane = threadIdx.x;
    float s = 0.f;
    #pragma unroll
    for (int j = 0; j < 4; ++j) {
        const int k = lane * 4 + j;
        s += bf2f(h2[r * 256 + k]) * Wout[k];
    }
    #pragma unroll
    for (int off = 32; off > 0; off >>= 1)
        s += __shfl_down(s, off, 64);
    if (lane == 0) {
        const float x = s + bout[0];
        out[r] = 1.f / (1.f + __expf(-x));
    }
}

// ======================= FALLBACK (verified round-0 kernel) =======================

#define BM 64
#define BN 64
#define BK 32
#define ADJ_LD 66

__global__ __launch_bounds__(256) void masked_gemm_kernel(
    const void* __restrict__ Av, int lda, int a_off, int a_f32,
    const float* __restrict__ W,
    const float* __restrict__ adj,
    const float* __restrict__ bias,
    u16* __restrict__ C, int ldc, int c_off,
    int N, int K)
{
    __shared__ __align__(16) u16 As[BM * BK];
    __shared__ __align__(16) u16 Bs[BN * BK];
    __shared__ __align__(16) u16 adjS[BK * ADJ_LD];

    const int t  = threadIdx.x;
    const int m0 = blockIdx.y * BM;
    const int n0 = blockIdx.x * BN;

    const int am = t >> 2;
    const int ak = (t & 3) * 8;
    const bool wvalid = (n0 + am) < N;
    const int jk = t >> 3;
    const int jn = (t & 7) * 8;

    const int lane  = t & 63;
    const int wave  = t >> 6;
    const int wm    = (wave >> 1) * 32;
    const int wnoff = (wave & 1) * 32;
    const int fr    = lane & 15;
    const int fq    = lane >> 4;
    const int kq    = fq * 8;

    const float* Af = (const float*)Av + (size_t)(m0 + am) * lda + a_off;
    const u16*   Ah = (const u16*)Av + (size_t)(m0 + am) * lda + a_off;
    const float* Wrow = W + (size_t)(n0 + am) * K;

    f32x4 acc[2][2] = {};

    const int nk = (K + BK - 1) / BK;
    for (int kt = 0; kt < nk; ++kt) {
        const int k0 = kt * BK;
        __syncthreads();
        {
            const int kg = k0 + ak;
            u16* dst = &As[am * BK + ak];
            if (a_f32) {
                if (kg + 8 <= K) {
                    float4 u0 = *(const float4*)&Af[kg];
                    float4 u1 = *(const float4*)&Af[kg + 4];
                    u16 tmp[8] = { f2bf(u0.x), f2bf(u0.y), f2bf(u0.z), f2bf(u0.w),
                                   f2bf(u1.x), f2bf(u1.y), f2bf(u1.z), f2bf(u1.w) };
                    *(uint4*)dst = *(const uint4*)tmp;
                } else {
                    #pragma unroll
                    for (int j = 0; j < 8; ++j)
                        dst[j] = (kg + j < K) ? f2bf(Af[kg + j]) : (u16)0;
                }
            } else {
                if (kg + 8 <= K) {
                    *(uint4*)dst = *(const uint4*)&Ah[kg];
                } else {
                    #pragma unroll
                    for (int j = 0; j < 8; ++j)
                        dst[j] = (kg + j < K) ? Ah[kg + j] : (u16)0;
                }
            }
        }
        {
            const int kg = k0 + ak;
            u16* dst = &Bs[am * BK + ak];
            if (wvalid && kg + 8 <= K) {
                float4 u0 = *(const float4*)&Wrow[kg];
                float4 u1 = *(const float4*)&Wrow[kg + 4];
                u16 tmp[8] = { f2bf(u0.x), f2bf(u0.y), f2bf(u0.z), f2bf(u0.w),
                               f2bf(u1.x), f2bf(u1.y), f2bf(u1.z), f2bf(u1.w) };
                *(uint4*)dst = *(const uint4*)tmp;
            } else {
                #pragma unroll
                for (int j = 0; j < 8; ++j)
                    dst[j] = (wvalid && kg + j < K) ? f2bf(Wrow[kg + j]) : (u16)0;
            }
        }
        if (adj) {
            const int kg = k0 + jk;
            u16* dst = &adjS[jk * ADJ_LD + jn];
            if (kg < K && n0 + jn + 8 <= N) {
                const float* ap = &adj[(size_t)kg * N + n0 + jn];
                float4 u0 = *(const float4*)&ap[0];
                float4 u1 = *(const float4*)&ap[4];
                u16 tmp[8] = { (u16)(u0.x != 0.f), (u16)(u0.y != 0.f),
                               (u16)(u0.z != 0.f), (u16)(u0.w != 0.f),
                               (u16)(u1.x != 0.f), (u16)(u1.y != 0.f),
                               (u16)(u1.z != 0.f), (u16)(u1.w != 0.f) };
                *(uint4*)dst = *(const uint4*)tmp;
            } else {
                #pragma unroll
                for (int j = 0; j < 8; ++j)
                    dst[j] = (kg < K && n0 + jn + j < N)
                                 ? (u16)(adj[(size_t)kg * N + n0 + jn + j] != 0.f) : (u16)0;
            }
            __syncthreads();
            #pragma unroll
            for (int j = 0; j < 8; ++j) {
                if (adjS[(ak + j) * ADJ_LD + am] == 0)
                    Bs[am * BK + ak + j] = 0;
            }
        }
        __syncthreads();

        bf16x8 a0 = *(const bf16x8*)&As[(wm + fr) * BK + kq];
        bf16x8 a1 = *(const bf16x8*)&As[(wm + 16 + fr) * BK + kq];
        bf16x8 b0 = *(const bf16x8*)&Bs[(wnoff + fr) * BK + kq];
        bf16x8 b1 = *(const bf16x8*)&Bs[(wnoff + 16 + fr) * BK + kq];
        acc[0][0] = __builtin_amdgcn_mfma_f32_16x16x32_bf16(a0, b0, acc[0][0], 0, 0, 0);
        acc[0][1] = __builtin_amdgcn_mfma_f32_16x16x32_bf16(a0, b1, acc[0][1], 0, 0, 0);
        acc[1][0] = __builtin_amdgcn_mfma_f32_16x16x32_bf16(a1, b0, acc[1][0], 0, 0, 0);
        acc[1][1] = __builtin_amdgcn_mfma_f32_16x16x32_bf16(a1, b1, acc[1][1], 0, 0, 0);
    }

    #pragma unroll
    for (int tn = 0; tn < 2; ++tn) {
        const int gcol = n0 + wnoff + tn * 16 + fr;
        if (gcol >= N) continue;
        const float bv = bias[gcol];
        #pragma unroll
        for (int tm = 0; tm < 2; ++tm) {
            #pragma unroll
            for (int r = 0; r < 4; ++r) {
                const int grow = m0 + wm + tm * 16 + fq * 4 + r;
                float v = acc[tm][tn][r] + bv;
                v = v > 0.f ? v : 0.f;
                C[(size_t)grow * ldc + c_off + gcol] = f2bf(v);
            }
        }
    }
}

// ======================= LAUNCH =======================

extern "C" void kernel_launch(void* const* d_in, const int* in_sizes, int n_in,
                              void* d_out, int out_size, void* d_ws, size_t ws_size,
                              hipStream_t stream) {
    const float* in_mat = (const float*)d_in[0];         // f32 512x28000
    const float* adj_sg = (const float*)d_in[1];
    const float* adj_gp = (const float*)d_in[2];
    const float* adj_br = (const float*)d_in[3];
    const float* adj_pp = (const float*)d_in[4];
    const float* W_sg = (const float*)d_in[5];   const float* b_sg = (const float*)d_in[6];
    const float* W_gp = (const float*)d_in[7];   const float* b_gp = (const float*)d_in[8];
    const float* W_br = (const float*)d_in[9];   const float* b_br = (const float*)d_in[10];
    const float* W_pp = (const float*)d_in[11];  const float* b_pp = (const float*)d_in[12];
    const float* W_h1 = (const float*)d_in[13];  const float* b_h1 = (const float*)d_in[14];
    const float* W_h2 = (const float*)d_in[15];  const float* b_h2 = (const float*)d_in[16];
    const float* W_out = (const float*)d_in[17]; const float* b_out = (const float*)d_in[18];

    const int KP_SG = 20032, KP_GP = 5056, KP_BR = 8000, KP_PP = 3008, KP_H1 = 6016, KP_H2 = 1024;
    const int NP_SG = 5056,  NP_GP = 3008, NP_BR = 3008, NP_PP = 3008, NP_H1 = 1024, NP_H2 = 256;

    u16* p = (u16*)d_ws;
    u16* Asnp = p;  p += (size_t)512 * KP_SG;
    u16* Agen = p;  p += (size_t)512 * KP_GP;
    u16* Apro = p;  p += (size_t)512 * KP_PP;
    u16* Wsg  = p;  p += (size_t)NP_SG * KP_SG;
    u16* Wgp  = p;  p += (size_t)NP_GP * KP_GP;
    u16* Wbr  = p;  p += (size_t)NP_BR * KP_BR;
    u16* Wpp  = p;  p += (size_t)NP_PP * KP_PP;
    u16* Wh1  = p;  p += (size_t)NP_H1 * KP_H1;
    u16* Wh2  = p;  p += (size_t)NP_H2 * KP_H2;
    u16* bridge = p; p += (size_t)512 * 8000;
    u16* fuse   = p; p += (size_t)512 * KP_H1;   // 512 x 6016
    u16* h1c    = p; p += (size_t)512 * 1024;
    u16* h2c    = p; p += (size_t)512 * 256;
    const size_t need_bytes = (size_t)(p - (u16*)d_ws) * 2;

    const dim3 blk(256);
    if (ws_size >= need_bytes) {
        // ---- prep: 6 masks + 3 converts + pad, one launch ----
        PrepBatch pb{};
        int base = 0;
        auto addm = [&](const float* W, const float* adj, u16* dst, int N, int K, int Kp, int Np) {
            int cnt = (Kp / 64) * (Np / 64);
            pb.t[pb.ntask++] = PrepTask{0, W, adj, dst, N, K, Kp, 0, 0, base, cnt};
            base += cnt;
        };
        auto addc = [&](int off, u16* dst, int K, int Kp, int cnt) {
            pb.t[pb.ntask++] = PrepTask{1, in_mat, nullptr, dst, 0, K, Kp, 28000, off, base, cnt};
            base += cnt;
        };
        addm(W_sg, adj_sg, Wsg, 5000, 20000, KP_SG, NP_SG);   // 24727
        addm(W_br, adj_br, Wbr, 3000, 8000,  KP_BR, NP_BR);   // 5875
        addm(W_gp, adj_gp, Wgp, 3000, 5000,  KP_GP, NP_GP);   // 3713
        addm(W_pp, adj_pp, Wpp, 3000, 3000,  KP_PP, NP_PP);   // 2209
        addm(W_h1, nullptr, Wh1, 1024, 6000, KP_H1, NP_H1);   // 1504
        addm(W_h2, nullptr, Wh2, 256, 1024,  KP_H2, NP_H2);   // 64
        addc(8000, Asnp, 20000, KP_SG, 1024);
        addc(3000, Agen, 5000,  KP_GP, 320);
        addc(0,    Apro, 3000,  KP_PP, 192);
        pb.t[pb.ntask++] = PrepTask{2, nullptr, nullptr, fuse, 0, 16, 0, KP_H1, 6000, base, 32};
        base += 32;
        prep_kernel<<<dim3(base), blk, 0, stream>>>(pb);

        // ---- GEMM chain: {L1,L2,L4} -> {L3} -> {L5} -> {L6} ----
        GemmBatch g1{};
        g1.t[0] = GemmTask{Asnp, Wsg, b_sg, bridge, KP_SG, KP_SG, 8000, 0,    5000, KP_SG / 64, 0};
        g1.t[1] = GemmTask{Agen, Wgp, b_gp, bridge, KP_GP, KP_GP, 8000, 5000, 3000, KP_GP / 64, 632};
        g1.t[2] = GemmTask{Apro, Wpp, b_pp, fuse,   KP_PP, KP_PP, KP_H1, 3000, 3000, KP_PP / 64, 1008};
        g1.ntask = 3;
        gemm_bf16_kernel<<<dim3(1384), blk, 0, stream>>>(g1);

        GemmBatch g2{};
        g2.t[0] = GemmTask{bridge, Wbr, b_br, fuse, 8000, KP_BR, KP_H1, 0, 3000, KP_BR / 64, 0};
        g2.ntask = 1;
        gemm_bf16_kernel<<<dim3(376), blk, 0, stream>>>(g2);

        GemmBatch g3{};
        g3.t[0] = GemmTask{fuse, Wh1, b_h1, h1c, KP_H1, KP_H1, 1024, 0, 1024, KP_H1 / 64, 0};
        g3.ntask = 1;
        gemm_bf16_kernel<<<dim3(128), blk, 0, stream>>>(g3);

        GemmBatch g4{};
        g4.t[0] = GemmTask{h1c, Wh2, b_h2, h2c, KP_H2, KP_H2, 256, 0, 256, KP_H2 / 64, 0};
        g4.ntask = 1;
        gemm_bf16_kernel<<<dim3(32), blk, 0, stream>>>(g4);

        final_kernel<<<dim3(512), dim3(64), 0, stream>>>(h2c, W_out, b_out, (float*)d_out);
    } else {
        // ---- fallback: verified round-0 path ----
        u16* ws      = (u16*)d_ws;
        u16* bridgeF = ws;
        u16* fuseF   = bridgeF + (size_t)512 * 8000;
        u16* h1F     = fuseF + (size_t)512 * 6000;
        u16* h2F     = h1F + (size_t)512 * 1024;

        masked_gemm_kernel<<<dim3((5000 + 63) / 64, 8), blk, 0, stream>>>(
            in_mat, 28000, 8000, 1, W_sg, adj_sg, b_sg, bridgeF, 8000, 0, 5000, 20000);
        masked_gemm_kernel<<<dim3((3000 + 63) / 64, 8), blk, 0, stream>>>(
            in_mat, 28000, 3000, 1, W_gp, adj_gp, b_gp, bridgeF, 8000, 5000, 3000, 5000);
        masked_gemm_kernel<<<dim3((3000 + 63) / 64, 8), blk, 0, stream>>>(
            bridgeF, 8000, 0, 0, W_br, adj_br, b_br, fuseF, 6000, 0, 3000, 8000);
        masked_gemm_kernel<<<dim3((3000 + 63) / 64, 8), blk, 0, stream>>>(
            in_mat, 28000, 0, 1, W_pp, adj_pp, b_pp, fuseF, 6000, 3000, 3000, 3000);
        masked_gemm_kernel<<<dim3(1024 / 64, 8), blk, 0, stream>>>(
            fuseF, 6000, 0, 0, W_h1, nullptr, b_h1, h1F, 1024, 0, 1024, 6000);
        masked_gemm_kernel<<<dim3(256 / 64, 8), blk, 0, stream>>>(
            h1F, 1024, 0, 0, W_h2, nullptr, b_h2, h2F, 256, 0, 256, 1024);
        final_kernel<<<dim3(512), dim3(64), 0, stream>>>(h2F, W_out, b_out, (float*)d_out);
    }
}